// Round 3
// baseline (244.472 us; speedup 1.0000x reference)
//
#include <hip/hip_runtime.h>
#include <hip/hip_bf16.h>
#include <math.h>

typedef short bf16x8 __attribute__((ext_vector_type(8)));
typedef float f32x4 __attribute__((ext_vector_type(4)));
typedef unsigned int u32;

#define B_DIM 8192
#define H_DIM 1024
#define NPATH 256
#define NSTEP 50

__device__ __forceinline__ void gld_lds16(const void* g, void* lds) {
  __builtin_amdgcn_global_load_lds(
      (const __attribute__((address_space(1))) u32*)g,
      (__attribute__((address_space(3))) u32*)lds, 16, 0, 0);
}

__device__ __forceinline__ void cast4(const float* in, __hip_bfloat16* out, int i) {
  float4 v = ((const float4*)in)[i];
  union { __hip_bfloat16 h[4]; short4 s; } u;
  u.h[0] = __float2bfloat16(v.x);
  u.h[1] = __float2bfloat16(v.y);
  u.h[2] = __float2bfloat16(v.z);
  u.h[3] = __float2bfloat16(v.w);
  ((short4*)out)[i] = u.s;
}

// ---------------- fused prep: casts + transposes + colsum(W_agg) ----------------
// roles by blockIdx:
//  [0,8192)        cast x -> xb
//  [8192,11264)    transpose+cast W_in/W_hid/W_out (1024 32x32 tiles each)
//  [11264,11520)   cast W_agg -> waggb
//  11520           cast W_fb -> wfbb
//  [11521,11525)   u[h] = DI * sum_p W_agg[p][h]
__global__ __launch_bounds__(256) void prep_kernel(
    const float* __restrict__ x, const float* __restrict__ W_in,
    const float* __restrict__ W_hid, const float* __restrict__ W_out,
    const float* __restrict__ W_agg, const float* __restrict__ W_fb,
    __hip_bfloat16* __restrict__ xb, __hip_bfloat16* __restrict__ wtin,
    __hip_bfloat16* __restrict__ wthid, __hip_bfloat16* __restrict__ wtout,
    __hip_bfloat16* __restrict__ waggb, __hip_bfloat16* __restrict__ wfbb,
    float* __restrict__ u, float DI) {
  __shared__ float t[32][33];
  int bid = blockIdx.x, tid = threadIdx.x;
  if (bid < 8192) {
    cast4(x, xb, bid * 256 + tid);
  } else if (bid < 11264) {
    int job = bid - 8192;
    const float* W; __hip_bfloat16* Wt;
    if (job < 1024)      { W = W_in;  Wt = wtin; }
    else if (job < 2048) { W = W_hid; Wt = wthid; job -= 1024; }
    else                 { W = W_out; Wt = wtout; job -= 2048; }
    int tX = job & 31, tY = job >> 5;
    int tx = tid & 31, r4 = tid >> 5;
#pragma unroll
    for (int i = 0; i < 4; ++i) {
      int ty = r4 * 4 + i;
      t[ty][tx] = W[(size_t)(tY * 32 + ty) * H_DIM + tX * 32 + tx];
    }
    __syncthreads();
#pragma unroll
    for (int i = 0; i < 4; ++i) {
      int ty = r4 * 4 + i;
      Wt[(size_t)(tX * 32 + ty) * H_DIM + tY * 32 + tx] = __float2bfloat16(t[tx][ty]);
    }
  } else if (bid < 11520) {
    cast4(W_agg, waggb, (bid - 11264) * 256 + tid);
  } else if (bid == 11520) {
    cast4(W_fb, wfbb, tid);  // 256 float4 = 1024 elems
  } else {
    int h = (bid - 11521) * 256 + tid;
    float s = 0.f;
#pragma unroll 8
    for (int p = 0; p < NPATH; ++p) s += W_agg[(size_t)p * H_DIM + h];
    u[h] = DI * s;
  }
}

// ---------------- shared GEMM K-loop core (128x128 tile, 4 waves) ----------------
// acc accumulates (not zeroed here). If FB, fbacc[m] accumulates dot(A_row, wfb)
// via an extra MFMA whose B-fragment is wfb broadcast to all 16 cols.
template <bool FB>
__device__ __forceinline__ void gemm_kloop(
    const __hip_bfloat16* __restrict__ A, int lda,
    const __hip_bfloat16* __restrict__ Bt, int ldb,
    const __hip_bfloat16* __restrict__ wfb,
    int K, int bm, int bn,
    __hip_bfloat16* As, __hip_bfloat16* Bs,
    f32x4 acc[4][4], f32x4* fbacc) {
  const int tid = threadIdx.x;
  const int lane = tid & 63;
  const int wid = tid >> 6;
  const int wr = wid >> 1, wc = wid & 1;
  const int frow = lane & 15;
  const int kgrp = lane >> 4;

  for (int kt = 0; kt < K; kt += 64) {
#pragma unroll
    for (int r = 0; r < 4; ++r) {
      int c = r * 256 + tid;
      int row = c >> 3;
      int cc = c & 7;
      const char* ga = (const char*)(A + (size_t)(bm * 128 + row) * lda + kt) + cc * 16;
      gld_lds16(ga, (char*)As + c * 16);
      const char* gb = (const char*)(Bt + (size_t)(bn * 128 + row) * ldb + kt) + cc * 16;
      gld_lds16(gb, (char*)Bs + c * 16);
    }
    __syncthreads();
#pragma unroll
    for (int kk = 0; kk < 64; kk += 32) {
      bf16x8 af[4], bfr[4];
#pragma unroll
      for (int m = 0; m < 4; ++m)
        af[m] = *(const bf16x8*)(As + (wr * 64 + m * 16 + frow) * 64 + kk + kgrp * 8);
#pragma unroll
      for (int n = 0; n < 4; ++n)
        bfr[n] = *(const bf16x8*)(Bs + (wc * 64 + n * 16 + frow) * 64 + kk + kgrp * 8);
      if (FB) {
        bf16x8 bfb = *(const bf16x8*)(wfb + kt + kk + kgrp * 8);
#pragma unroll
        for (int m = 0; m < 4; ++m)
          fbacc[m] = __builtin_amdgcn_mfma_f32_16x16x32_bf16(af[m], bfb, fbacc[m], 0, 0, 0);
      }
#pragma unroll
      for (int m = 0; m < 4; ++m)
#pragma unroll
        for (int n = 0; n < 4; ++n)
          acc[m][n] = __builtin_amdgcn_mfma_f32_16x16x32_bf16(af[m], bfr[n], acc[m][n], 0, 0, 0);
    }
    __syncthreads();
  }
}

// epilogue: C/D layout col = lane&15, row = (lane>>4)*4 + j  [verified mapping]
// MODE 0: relu(acc+bias) -> bf16 ; MODE 1: acc -> bf16 (no bias)
template <int MODE>
__device__ __forceinline__ void epilogue_bf16(f32x4 acc[4][4], const float* bias,
                                              __hip_bfloat16* out, int N, int bm, int bn) {
  const int lane = threadIdx.x & 63;
  const int wid = threadIdx.x >> 6;
  const int wr = wid >> 1, wc = wid & 1;
  const int frow = lane & 15, kgrp = lane >> 4;
  const int r0 = bm * 128 + wr * 64;
  const int c0 = bn * 128 + wc * 64;
#pragma unroll
  for (int n = 0; n < 4; ++n) {
    int col = c0 + n * 16 + frow;
    float bv = (MODE == 0) ? bias[col] : 0.f;
#pragma unroll
    for (int m = 0; m < 4; ++m)
#pragma unroll
      for (int j = 0; j < 4; ++j) {
        int row = r0 + m * 16 + kgrp * 4 + j;
        float v = acc[m][n][j] + bv;
        if (MODE == 0) v = fmaxf(v, 0.f);
        out[(size_t)row * N + col] = __float2bfloat16(v);
      }
  }
}

// ---------------- stage kernel: trunk GEMM + co-scheduled noise (+ tail jobs) ----
// bid in [0,1024): odd -> GEMM tile, even -> noise reduction chunk
// bid in [1024,1040): WcT = wtout @ waggb^T  (stage2 only)
// bid in [1040,1044): v1/v2 vectors          (stage2 only)
__global__ __launch_bounds__(256) void stage_kernel(
    const __hip_bfloat16* __restrict__ A, const __hip_bfloat16* __restrict__ Bt,
    const float* __restrict__ bias, __hip_bfloat16* __restrict__ out,
    const float* __restrict__ noise, __hip_bfloat16* __restrict__ sb,
    int rowStart, int rowCount, float SQDT,
    const __hip_bfloat16* __restrict__ wtout, const __hip_bfloat16* __restrict__ waggb,
    __hip_bfloat16* __restrict__ wct,
    const float* __restrict__ u, const float* __restrict__ W_out,
    const float* __restrict__ b_agg, const float* __restrict__ b_out,
    float* __restrict__ v1, float* __restrict__ v2) {
  __shared__ __hip_bfloat16 As[128 * 64];
  __shared__ __hip_bfloat16 Bs[128 * 64];
  int bid = blockIdx.x;
  if (bid < 1024) {
    if (bid & 1) {
      int gb = bid >> 1;  // bm = gb>>3, bn = gb&7  (N=1024)
      f32x4 acc[4][4];
#pragma unroll
      for (int m = 0; m < 4; ++m)
#pragma unroll
        for (int n = 0; n < 4; ++n) acc[m][n] = (f32x4){0.f, 0.f, 0.f, 0.f};
      gemm_kloop<false>(A, H_DIM, Bt, H_DIM, nullptr, H_DIM, gb >> 3, gb & 7, As, Bs, acc, nullptr);
      epilogue_bf16<0>(acc, bias, out, H_DIM, gb >> 3, gb & 7);
    } else {
      int j = bid >> 1;  // 512 noise blocks, grid-stride over rowCount
      for (int r = j * 256 + threadIdx.x; r < rowCount; r += 512 * 256) {
        int row = rowStart + r;
        const float2* p = (const float2*)(noise + (size_t)row * NSTEP);
        float s = 0.f;
#pragma unroll
        for (int i = 0; i < NSTEP / 2; ++i) {
          float2 v = p[i];
          s += v.x + v.y;
        }
        sb[row] = __float2bfloat16(SQDT * s);
      }
    }
  } else if (bid < 1040) {
    int gb = bid - 1024;  // M=1024, N=256: bm = gb>>1 (0..7), bn = gb&1
    f32x4 acc[4][4];
#pragma unroll
    for (int m = 0; m < 4; ++m)
#pragma unroll
      for (int n = 0; n < 4; ++n) acc[m][n] = (f32x4){0.f, 0.f, 0.f, 0.f};
    gemm_kloop<false>(wtout, H_DIM, waggb, H_DIM, nullptr, H_DIM, gb >> 1, gb & 1, As, Bs, acc, nullptr);
    epilogue_bf16<1>(acc, nullptr, wct, NPATH, gb >> 1, gb & 1);
  } else {
    int d = (bid - 1040) * 256 + threadIdx.x;
    float s1 = 0.f, s2 = 0.f;
#pragma unroll 8
    for (int h = 0; h < H_DIM; ++h) {
      float w = W_out[(size_t)h * H_DIM + d];
      s1 += u[h] * w;
      s2 += b_agg[h] * w;
    }
    v1[d] = s1;
    v2[d] = s2 + b_out[d];
  }
}

// ---------------- final fused GEMM: out = h2@W_out + sb@Wc^T + fb*v1 + v2 -------
__global__ __launch_bounds__(256) void final_kernel(
    const __hip_bfloat16* __restrict__ h2b, const __hip_bfloat16* __restrict__ wtout,
    const __hip_bfloat16* __restrict__ sb, const __hip_bfloat16* __restrict__ wct,
    const __hip_bfloat16* __restrict__ wfbb, const float* __restrict__ bfb,
    const float* __restrict__ v1, const float* __restrict__ v2,
    float* __restrict__ out) {
  __shared__ __hip_bfloat16 As[128 * 64];
  __shared__ __hip_bfloat16 Bs[128 * 64];
  int gb = blockIdx.x;  // 512: bm = gb>>3, bn = gb&7
  const int bm = gb >> 3, bn = gb & 7;
  f32x4 acc[4][4];
  f32x4 fbacc[4];
#pragma unroll
  for (int m = 0; m < 4; ++m) {
    fbacc[m] = (f32x4){0.f, 0.f, 0.f, 0.f};
#pragma unroll
    for (int n = 0; n < 4; ++n) acc[m][n] = (f32x4){0.f, 0.f, 0.f, 0.f};
  }
  // phase 1: h2 @ W_out (K=1024) with fused feedback column
  gemm_kloop<true>(h2b, H_DIM, wtout, H_DIM, wfbb, H_DIM, bm, bn, As, Bs, acc, fbacc);
  // phase 2: (SQDT*ns) @ Wc^T (K=256)
  gemm_kloop<false>(sb, NPATH, wct, NPATH, nullptr, NPATH, bm, bn, As, Bs, acc, nullptr);

  const int lane = threadIdx.x & 63;
  const int wid = threadIdx.x >> 6;
  const int wr = wid >> 1, wc = wid & 1;
  const int frow = lane & 15, kgrp = lane >> 4;
  const float bfb0 = bfb[0];
  float fbv[4][4];
#pragma unroll
  for (int m = 0; m < 4; ++m)
#pragma unroll
    for (int j = 0; j < 4; ++j)
      fbv[m][j] = 1.0f / (1.0f + expf(-(fbacc[m][j] + bfb0)));

  const int r0 = bm * 128 + wr * 64;
  const int c0 = bn * 128 + wc * 64;
#pragma unroll
  for (int n = 0; n < 4; ++n) {
    int col = c0 + n * 16 + frow;
    float v1c = v1[col], v2c = v2[col];
#pragma unroll
    for (int m = 0; m < 4; ++m)
#pragma unroll
      for (int j = 0; j < 4; ++j) {
        int row = r0 + m * 16 + kgrp * 4 + j;
        out[(size_t)row * H_DIM + col] = acc[m][n][j] + fbv[m][j] * v1c + v2c;
      }
  }
}

extern "C" void kernel_launch(void* const* d_in, const int* in_sizes, int n_in,
                              void* d_out, int out_size, void* d_ws, size_t ws_size,
                              hipStream_t stream) {
  (void)in_sizes; (void)n_in; (void)out_size;
  const float* x     = (const float*)d_in[0];
  const float* W_in  = (const float*)d_in[1];
  const float* b_in  = (const float*)d_in[2];
  const float* W_hid = (const float*)d_in[3];
  const float* b_hid = (const float*)d_in[4];
  const float* W_fb  = (const float*)d_in[5];
  const float* b_fb  = (const float*)d_in[6];
  const float* W_agg = (const float*)d_in[7];
  const float* b_agg = (const float*)d_in[8];
  const float* W_out = (const float*)d_in[9];
  const float* b_out = (const float*)d_in[10];
  const float* noise = (const float*)d_in[11];

  const int B = B_DIM, H = H_DIM, P = NPATH;
  const int R = B * P;

  size_t off = 0;
  char* base = (char*)d_ws;
  auto take = [&](size_t bytes) -> char* {
    char* r = base + off;
    off = (off + bytes + 255) & ~(size_t)255;
    return r;
  };
  __hip_bfloat16* xb    = (__hip_bfloat16*)take((size_t)B * H * 2);  // reused as h2b
  __hip_bfloat16* h2b   = xb;                                        // alias: xb dead after stage2
  __hip_bfloat16* wtin  = (__hip_bfloat16*)take((size_t)H * H * 2);
  __hip_bfloat16* wthid = (__hip_bfloat16*)take((size_t)H * H * 2);
  __hip_bfloat16* wtout = (__hip_bfloat16*)take((size_t)H * H * 2);
  __hip_bfloat16* waggb = (__hip_bfloat16*)take((size_t)P * H * 2);
  __hip_bfloat16* wct   = (__hip_bfloat16*)take((size_t)H * P * 2);
  __hip_bfloat16* wfbb  = (__hip_bfloat16*)take((size_t)H * 2);
  float* u  = (float*)take((size_t)H * 4);
  float* v1 = (float*)take((size_t)H * 4);
  float* v2 = (float*)take((size_t)H * 4);
  __hip_bfloat16* sb = (__hip_bfloat16*)take((size_t)R * 2);

  __hip_bfloat16* h1b;
  if (ws_size >= off + (size_t)B * H * 2) {
    h1b = (__hip_bfloat16*)take((size_t)B * H * 2);
  } else {
    // d_out (32MB fp32) is dead until final_kernel; h1b dies before it runs
    h1b = (__hip_bfloat16*)d_out;
  }

  float dt = 1.0f / NSTEP;
  float DI = 0.f;
  for (int j = 0; j < NSTEP; ++j) DI += expf(-0.1f * ((float)j * dt));
  DI *= dt;
  float SQDT = sqrtf(dt);

  prep_kernel<<<11525, 256, 0, stream>>>(x, W_in, W_hid, W_out, W_agg, W_fb,
                                         xb, wtin, wthid, wtout, waggb, wfbb, u, DI);
  // stage 2: x@W_in (relu) + noise half 1 + WcT GEMM + v1/v2 tail jobs
  stage_kernel<<<1044, 256, 0, stream>>>(xb, wtin, b_in, h1b, noise, sb, 0, R / 2, SQDT,
                                         wtout, waggb, wct, u, W_out, b_agg, b_out, v1, v2);
  // stage 3: h1@W_hid (relu) + noise half 2
  stage_kernel<<<1024, 256, 0, stream>>>(h1b, wthid, b_hid, h2b, noise, sb, R / 2, R - R / 2, SQDT,
                                         wtout, waggb, wct, u, W_out, b_agg, b_out, v1, v2);
  // final: out = h2@W_out + sb@Wc^T + sigmoid(h2@W_fb + b_fb)*v1 + v2
  final_kernel<<<512, 256, 0, stream>>>(h2b, wtout, sb, wct, wfbb, b_fb, v1, v2, (float*)d_out);
}

// Round 4
// 205.158 us; speedup vs baseline: 1.1916x; 1.1916x over previous
//
#include <hip/hip_runtime.h>
#include <hip/hip_bf16.h>
#include <math.h>

typedef short bf16x8 __attribute__((ext_vector_type(8)));
typedef float f32x4 __attribute__((ext_vector_type(4)));
typedef unsigned int u32;

#define B_DIM 8192
#define H_DIM 1024
#define NPATH 256
#define NSTEP 50

__device__ __forceinline__ void gld_lds16(const void* g, void* lds) {
  __builtin_amdgcn_global_load_lds(
      (const __attribute__((address_space(1))) u32*)g,
      (__attribute__((address_space(3))) u32*)lds, 16, 0, 0);
}

__device__ __forceinline__ void cast4(const float* in, __hip_bfloat16* out, int i) {
  float4 v = ((const float4*)in)[i];
  union { __hip_bfloat16 h[4]; short4 s; } u;
  u.h[0] = __float2bfloat16(v.x);
  u.h[1] = __float2bfloat16(v.y);
  u.h[2] = __float2bfloat16(v.z);
  u.h[3] = __float2bfloat16(v.w);
  ((short4*)out)[i] = u.s;
}

// ---------------- fused prep: x cast + 4 weight transposes ----------------
// roles by blockIdx:
//  [0,8192)        cast x -> xb
//  [8192,11264)    transpose+cast W_in/W_hid/W_out (1024 32x32 tiles each)
//  [11264,11520)   transpose+cast W_agg (256 tiles)
__global__ __launch_bounds__(256) void prep_kernel(
    const float* __restrict__ x, const float* __restrict__ W_in,
    const float* __restrict__ W_hid, const float* __restrict__ W_out,
    const float* __restrict__ W_agg,
    __hip_bfloat16* __restrict__ xb, __hip_bfloat16* __restrict__ wtin,
    __hip_bfloat16* __restrict__ wthid, __hip_bfloat16* __restrict__ wtout,
    __hip_bfloat16* __restrict__ wtagg) {
  __shared__ float t[32][33];
  int bid = blockIdx.x, tid = threadIdx.x;
  if (bid < 8192) {
    cast4(x, xb, bid * 256 + tid);
    return;
  }
  int job = bid - 8192;
  const float* W; __hip_bfloat16* Wt; int R, C;
  if (job < 1024)      { W = W_in;  Wt = wtin;  R = 1024; C = 1024; }
  else if (job < 2048) { W = W_hid; Wt = wthid; R = 1024; C = 1024; job -= 1024; }
  else if (job < 3072) { W = W_out; Wt = wtout; R = 1024; C = 1024; job -= 2048; }
  else                 { W = W_agg; Wt = wtagg; R = 256;  C = 1024; job -= 3072; }
  int nTx = C / 32;
  int tX = job % nTx, tY = job / nTx;
  int tx = tid & 31, r4 = tid >> 5;
#pragma unroll
  for (int i = 0; i < 4; ++i) {
    int ty = r4 * 4 + i;
    t[ty][tx] = W[(size_t)(tY * 32 + ty) * C + tX * 32 + tx];
  }
  __syncthreads();
#pragma unroll
  for (int i = 0; i < 4; ++i) {
    int ty = r4 * 4 + i;
    Wt[(size_t)(tX * 32 + ty) * R + tY * 32 + tx] = __float2bfloat16(t[tx][ty]);
  }
}

// ------------- fused feedback + endpoints: per block = 4 batch rows -------------
__global__ __launch_bounds__(256) void fb_end_kernel(
    const __hip_bfloat16* __restrict__ h2b, const float* __restrict__ Wfb,
    const float* __restrict__ bfb, const float* __restrict__ ns,
    __hip_bfloat16* __restrict__ eb, float DI, float SQDT) {
  __shared__ float fv[4];
  int wid = threadIdx.x >> 6, lane = threadIdx.x & 63;
  int row = blockIdx.x * 4 + wid;
  const __hip_bfloat16* hrow = h2b + (size_t)row * H_DIM;
  float s = 0.f;
#pragma unroll
  for (int i = lane; i < H_DIM; i += 64) s += __bfloat162float(hrow[i]) * Wfb[i];
#pragma unroll
  for (int off = 32; off > 0; off >>= 1) s += __shfl_down(s, off);
  if (lane == 0) fv[wid] = 1.0f / (1.0f + expf(-(s + bfb[0])));
  __syncthreads();
#pragma unroll
  for (int w = 0; w < 4; ++w) {
    size_t i = (size_t)(blockIdx.x * 4 + w) * NPATH + threadIdx.x;
    eb[i] = __float2bfloat16(fv[w] * DI + SQDT * ns[i]);
  }
}

// ---------------- pipelined 256-row-tile MFMA GEMM core ----------------
// BM=256, BN=TBN (256 or 128), BK=64, 8 waves (2M x 4N), per-wave 128 x TBN/4.
// T3/T4: next K-tile staged via global_load_lds while computing current;
//        counted s_waitcnt vmcnt(N) + raw s_barrier (no vmcnt(0) drain in loop).
// T2:    LDS XOR swizzle byte ^= (row&7)<<4, applied as pre-swizzled global
//        source (write side) + swizzled read address (rule #21 pairing).
// MODE 0: relu(acc+bias) -> bf16 ; MODE 2: acc+bias+extra -> bf16 ; MODE 3: fp32.
// NOISE: blocks >= nGemm reduce noise rows into ns (f32) instead.
template <int TBN, int MODE, bool NOISE>
__global__ __launch_bounds__(512) void gemm8(
    const __hip_bfloat16* __restrict__ A, const __hip_bfloat16* __restrict__ Bt,
    const float* __restrict__ bias, const __hip_bfloat16* __restrict__ extra,
    void* __restrict__ out, int N, int K,
    int nGemm, const float* __restrict__ noise, float* __restrict__ ns,
    int rowStart, int rowCount) {
  constexpr int NR = TBN / 64;                 // per-wave n-fragments: 4 or 2
  constexpr int SMHALF = (256 + TBN) * 64 * 2; // bytes per double-buffer half
  constexpr int NLOADS = (256 + TBN) / 64;     // gld_lds16 per thread per stage: 8 or 6
  __shared__ char smem[2 * SMHALF];

  if (NOISE && blockIdx.x >= nGemm) {
    int j = blockIdx.x - nGemm;
    int stride = (gridDim.x - nGemm) * 512;
    for (int r = j * 512 + threadIdx.x; r < rowCount; r += stride) {
      const float2* p = (const float2*)(noise + (size_t)(rowStart + r) * NSTEP);
      float s = 0.f;
#pragma unroll
      for (int i = 0; i < NSTEP / 2; ++i) { float2 v = p[i]; s += v.x + v.y; }
      ns[rowStart + r] = s;
    }
    return;
  }

  const int tid = threadIdx.x;
  const int lane = tid & 63, wid = tid >> 6;
  const int wm = wid >> 2, wn = wid & 3;
  const int frow = lane & 15, kgrp = lane >> 4;
  const int gx = N / TBN;
  const int bm = blockIdx.x / gx, bn = blockIdx.x % gx;
  const size_t arow0 = (size_t)(bm * 256) * K;
  const size_t brow0 = (size_t)(bn * TBN) * K;

  auto stage = [&](int kt, int d) {
    char* dst = smem + d * SMHALF;
#pragma unroll
    for (int j = 0; j < NLOADS; ++j) {
      int c = j * 512 + tid;
      if (j < 4) {  // A tile: 256x64 = 2048 16B-chunks
        int row = c >> 3, cb = (c & 7) * 16;
        int col = (cb ^ ((row & 7) << 4)) >> 1;  // pre-swizzled source column
        gld_lds16((const void*)(A + arow0 + (size_t)row * K + kt + col), dst + c * 16);
      } else {      // B tile: TBN x 64
        int cB = c - 2048;
        int row = cB >> 3, cb = (cB & 7) * 16;
        int col = (cb ^ ((row & 7) << 4)) >> 1;
        gld_lds16((const void*)(Bt + brow0 + (size_t)row * K + kt + col), dst + 32768 + cB * 16);
      }
    }
  };

  f32x4 acc[8][NR];
#pragma unroll
  for (int m = 0; m < 8; ++m)
#pragma unroll
    for (int n = 0; n < NR; ++n) acc[m][n] = (f32x4){0.f, 0.f, 0.f, 0.f};

  stage(0, 0);
  const int NT = K >> 6;
  for (int t = 0; t < NT; ++t) {
    const int cur = t & 1;
    if (t + 1 < NT) stage((t + 1) << 6, cur ^ 1);
    if (t == 0 || t + 1 >= NT) {
      asm volatile("s_waitcnt vmcnt(0)" ::: "memory");
    } else if constexpr (TBN == 256) {
      asm volatile("s_waitcnt vmcnt(8)" ::: "memory");
    } else {
      asm volatile("s_waitcnt vmcnt(6)" ::: "memory");
    }
    __builtin_amdgcn_s_barrier();

    const char* Ab = smem + cur * SMHALF;
    const char* Bb = Ab + 32768;
    bf16x8 bfr[NR][2];
#pragma unroll
    for (int n = 0; n < NR; ++n)
#pragma unroll
      for (int s = 0; s < 2; ++s) {
        int row = wn * (NR * 16) + n * 16 + frow;
        int cb = s * 64 + kgrp * 16;
        bfr[n][s] = *(const bf16x8*)(Bb + row * 128 + (cb ^ ((row & 7) << 4)));
      }
#pragma unroll
    for (int mh = 0; mh < 2; ++mh) {
      bf16x8 af[4][2];
#pragma unroll
      for (int m = 0; m < 4; ++m)
#pragma unroll
        for (int s = 0; s < 2; ++s) {
          int row = wm * 128 + (mh * 4 + m) * 16 + frow;
          int cb = s * 64 + kgrp * 16;
          af[m][s] = *(const bf16x8*)(Ab + row * 128 + (cb ^ ((row & 7) << 4)));
        }
#pragma unroll
      for (int m = 0; m < 4; ++m)
#pragma unroll
        for (int n = 0; n < NR; ++n)
#pragma unroll
          for (int s = 0; s < 2; ++s)
            acc[mh * 4 + m][n] = __builtin_amdgcn_mfma_f32_16x16x32_bf16(
                af[m][s], bfr[n][s], acc[mh * 4 + m][n], 0, 0, 0);
    }
    __builtin_amdgcn_s_barrier();  // all waves done reading buf[cur] before overwrite
  }

  // epilogue: C/D layout col = lane&15, row = (lane>>4)*4 + j  [verified mapping]
  const int r0 = bm * 256 + wm * 128;
  const int c0 = bn * TBN + wn * (NR * 16);
#pragma unroll
  for (int n = 0; n < NR; ++n) {
    int col = c0 + n * 16 + frow;
    float bv = bias[col];
#pragma unroll
    for (int m = 0; m < 8; ++m)
#pragma unroll
      for (int j = 0; j < 4; ++j) {
        int row = r0 + m * 16 + kgrp * 4 + j;
        float v = acc[m][n][j] + bv;
        if (MODE == 0) {
          v = fmaxf(v, 0.f);
          ((__hip_bfloat16*)out)[(size_t)row * N + col] = __float2bfloat16(v);
        } else if (MODE == 2) {
          v += __bfloat162float(extra[(size_t)row * N + col]);
          ((__hip_bfloat16*)out)[(size_t)row * N + col] = __float2bfloat16(v);
        } else {
          ((float*)out)[(size_t)row * N + col] = v;
        }
      }
  }
}

extern "C" void kernel_launch(void* const* d_in, const int* in_sizes, int n_in,
                              void* d_out, int out_size, void* d_ws, size_t ws_size,
                              hipStream_t stream) {
  (void)in_sizes; (void)n_in; (void)out_size; (void)ws_size;
  const float* x     = (const float*)d_in[0];
  const float* W_in  = (const float*)d_in[1];
  const float* b_in  = (const float*)d_in[2];
  const float* W_hid = (const float*)d_in[3];
  const float* b_hid = (const float*)d_in[4];
  const float* W_fb  = (const float*)d_in[5];
  const float* b_fb  = (const float*)d_in[6];
  const float* W_agg = (const float*)d_in[7];
  const float* b_agg = (const float*)d_in[8];
  const float* W_out = (const float*)d_in[9];
  const float* b_out = (const float*)d_in[10];
  const float* noise = (const float*)d_in[11];

  const int B = B_DIM, H = H_DIM, P = NPATH;
  const int R = B * P;

  size_t off = 0;
  char* base = (char*)d_ws;
  auto take = [&](size_t bytes) -> char* {
    char* r = base + off;
    off = (off + bytes + 255) & ~(size_t)255;
    return r;
  };
  __hip_bfloat16* xb    = (__hip_bfloat16*)take((size_t)B * H * 2);  // reused as `combined`
  __hip_bfloat16* h1b   = (__hip_bfloat16*)take((size_t)B * H * 2);
  __hip_bfloat16* h2b   = (__hip_bfloat16*)take((size_t)B * H * 2);
  __hip_bfloat16* wtin  = (__hip_bfloat16*)take((size_t)H * H * 2);
  __hip_bfloat16* wthid = (__hip_bfloat16*)take((size_t)H * H * 2);
  __hip_bfloat16* wtout = (__hip_bfloat16*)take((size_t)H * H * 2);
  __hip_bfloat16* wtagg = (__hip_bfloat16*)take((size_t)H * P * 2);
  float* ns = (float*)take((size_t)R * 4);
  __hip_bfloat16* eb = (__hip_bfloat16*)take((size_t)R * 2);

  float dt = 1.0f / NSTEP;
  float DI = 0.f;
  for (int j = 0; j < NSTEP; ++j) DI += expf(-0.1f * ((float)j * dt));
  DI *= dt;
  float SQDT = sqrtf(dt);

  prep_kernel<<<11520, 256, 0, stream>>>(x, W_in, W_hid, W_out, W_agg,
                                         xb, wtin, wthid, wtout, wtagg);

  // trunk GEMMs (128 tiles of 256x256) + co-scheduled noise reduction halves
  gemm8<256, 0, true><<<384, 512, 0, stream>>>(xb, wtin, b_in, nullptr, h1b,
                                               H, H, 128, noise, ns, 0, R / 2);
  gemm8<256, 0, true><<<384, 512, 0, stream>>>(h1b, wthid, b_hid, nullptr, h2b,
                                               H, H, 128, noise, ns, R / 2, R - R / 2);
  fb_end_kernel<<<B / 4, 256, 0, stream>>>(h2b, W_fb, b_fb, ns, eb, DI, SQDT);
  // bicep: eb @ wtagg^T + b_agg + h2 -> xb (combined), K=256
  gemm8<128, 2, false><<<256, 512, 0, stream>>>(eb, wtagg, b_agg, h2b, xb,
                                                H, P, 256, nullptr, nullptr, 0, 0);
  // final: combined @ W_out^T + b_out -> fp32 d_out, K=1024
  gemm8<128, 3, false><<<256, 512, 0, stream>>>(xb, wtout, b_out, nullptr, d_out,
                                                H, H, 256, nullptr, nullptr, 0, 0);
}